// Round 1
// baseline (1069.502 us; speedup 1.0000x reference)
//
#include <hip/hip_runtime.h>
#include <math.h>

// Problem constants
#define NB 1024      // batch
#define LL 128       // max length
#define HH 512       // hidden
#define OO 32000     // vocab

typedef __attribute__((ext_vector_type(8))) short bf16x8;
typedef __attribute__((ext_vector_type(4))) float f32x4;
typedef __attribute__((ext_vector_type(4))) unsigned short us4;

// bf16 round-to-nearest-even helpers
static __device__ inline unsigned short f2bf(float x) {
    unsigned int u = __float_as_uint(x);
    unsigned int r = u + 0x7FFF + ((u >> 16) & 1);
    return (unsigned short)(r >> 16);
}
static __device__ inline float bf2f(unsigned short b) {
    return __uint_as_float(((unsigned int)b) << 16);
}

// ---------------------------------------------------------------------------
// Tiled fp32 SGEMM:  C[m][n] = act( sum_k A[m][k]*B[n][k] + bias[n] )
// A: [M,K] row-major, B: [N,K] row-major (i.e. C = A @ B^T), K%16==0, M,N%64==0
// ACT: 0 = none, 1 = relu
// ---------------------------------------------------------------------------
template<int ACT>
__global__ __launch_bounds__(256) void sgemm_bias(
    const float* __restrict__ A, const float* __restrict__ B,
    const float* __restrict__ bias, float* __restrict__ C,
    int M, int Ncols, int K)
{
    const int BM = 64, BN = 64, BK = 16;
    __shared__ float As[BK][BM];
    __shared__ float Bs[BK][BN];

    const int bm = blockIdx.y * BM;
    const int bn = blockIdx.x * BN;
    const int tid = threadIdx.x;          // 256 threads
    const int tr = tid / 16;              // 0..15
    const int tc = tid % 16;              // 0..15

    const int lr = tid / 4;               // 0..63 (row within tile)
    const int lk = (tid % 4) * 4;         // 0,4,8,12 (k offset)

    float acc[4][4] = {};

    for (int k0 = 0; k0 < K; k0 += BK) {
        float4 a4 = *(const float4*)&A[(size_t)(bm + lr) * K + k0 + lk];
        float4 b4 = *(const float4*)&B[(size_t)(bn + lr) * K + k0 + lk];
        __syncthreads();   // previous iteration's reads done before overwrite
        As[lk + 0][lr] = a4.x; As[lk + 1][lr] = a4.y;
        As[lk + 2][lr] = a4.z; As[lk + 3][lr] = a4.w;
        Bs[lk + 0][lr] = b4.x; Bs[lk + 1][lr] = b4.y;
        Bs[lk + 2][lr] = b4.z; Bs[lk + 3][lr] = b4.w;
        __syncthreads();
        #pragma unroll
        for (int k = 0; k < BK; ++k) {
            float4 av = *(const float4*)&As[k][tr * 4];
            float4 bv = *(const float4*)&Bs[k][tc * 4];
            float a[4] = {av.x, av.y, av.z, av.w};
            float b[4] = {bv.x, bv.y, bv.z, bv.w};
            #pragma unroll
            for (int i = 0; i < 4; ++i)
                #pragma unroll
                for (int j = 0; j < 4; ++j)
                    acc[i][j] += a[i] * b[j];
        }
    }

    #pragma unroll
    for (int i = 0; i < 4; ++i) {
        int row = bm + tr * 4 + i;
        #pragma unroll
        for (int j = 0; j < 4; ++j) {
            int col = bn + tc * 4 + j;
            float v = acc[i][j] + bias[col];
            if (ACT == 1) v = fmaxf(v, 0.0f);
            C[(size_t)row * Ncols + col] = v;
        }
    }
}

// ---------------------------------------------------------------------------
// Split out_W fp32 -> B2 bf16 [32000][1024]  (hi | lo halves along K)
// ---------------------------------------------------------------------------
__global__ __launch_bounds__(256) void split_w(const float* __restrict__ W,
                                               unsigned short* __restrict__ B2)
{
    int idx = blockIdx.x * blockDim.x + threadIdx.x;   // 32000*128
    float4 v = ((const float4*)W)[idx];
    int o  = idx >> 7;            // row (128 float4 per row of 512)
    int k4 = (idx & 127) * 4;
    float x[4] = {v.x, v.y, v.z, v.w};
    us4 hi, lo;
    #pragma unroll
    for (int i = 0; i < 4; ++i) {
        unsigned short h = f2bf(x[i]);
        hi[i] = h;
        lo[i] = f2bf(x[i] - bf2f(h));
    }
    *(us4*)&B2[(size_t)o * 1024 + k4]       = hi;
    *(us4*)&B2[(size_t)o * 1024 + 512 + k4] = lo;
}

// ---------------------------------------------------------------------------
// bf16x3 MFMA GEMM for the output projection.
// A2: [1024][1024] bf16 (hi|lo of h_new), B2: [32000][1024] bf16 (hi|lo of W)
// Virtual K' = 1536 = [hiA*hiB | hiA*loB | loA*hiB] via segment address remap.
// C[1024][32000] fp32 = sum + bias.  Tile 128x128, 4 waves, BK=32, dbuf LDS,
// global_load_lds(16B) with source-side XOR slot swizzle (involution).
// ---------------------------------------------------------------------------
__global__ __launch_bounds__(256) void gemm_bf16x3(
    const unsigned short* __restrict__ A2,
    const unsigned short* __restrict__ B2,
    const float* __restrict__ bias,
    float* __restrict__ C)
{
    __shared__ __align__(16) unsigned short sA[2][128][32];
    __shared__ __align__(16) unsigned short sB[2][128][32];

    // XCD-chunked swizzle: 2000 blocks, 8 XCDs, 250 per XCD; m-tile cycles
    // fastest within a chunk so the 8 blocks sharing a B-panel are co-XCD.
    const int bid = blockIdx.x;
    const int swz = (bid & 7) * 250 + (bid >> 3);
    const int mt = swz & 7;        // 0..7   (M tile)
    const int nt = swz >> 3;       // 0..249 (N tile)
    const int tileM = mt * 128;
    const int tileN = nt * 128;

    const int tid  = threadIdx.x;
    const int w    = tid >> 6;       // wave 0..3
    const int lane = tid & 63;
    const int wr   = w >> 1;         // wave row (0..1) -> 64 rows
    const int wc   = w & 1;          // wave col (0..1) -> 64 cols

    const int sr = lane >> 2;        // staging: row within 16-row group
    const int st = lane & 3;         // staging: 16B slot within 64B row

    typedef const __attribute__((address_space(1))) unsigned int g_u32;
    typedef __attribute__((address_space(3))) unsigned int l_u32;

    f32x4 acc[4][4] = {};

    // stage one 128x32 bf16 tile of A and B for virtual k0 = kk into buf
    auto stage = [&](int buf, int kk) {
        // segment remap: kk in [0,512):   hiA * hiB
        //                kk in [512,1024): hiA * loB
        //                kk in [1024,1536): loA * hiB
        int kA = (kk < 512) ? kk : kk - 512;     // hi,hi,lo
        int kB = (kk < 1024) ? kk : kk - 1024;   // hi,lo,hi
        #pragma unroll
        for (int rd = 0; rd < 2; ++rd) {
            int r  = rd * 64 + w * 16 + sr;          // row within tile
            int su = st ^ ((r >> 1) & 3);            // source slot (involution)
            const unsigned short* ga = A2 + (size_t)(tileM + r) * 1024 + kA + su * 8;
            const unsigned short* gb = B2 + (size_t)(tileN + r) * 1024 + kB + su * 8;
            __builtin_amdgcn_global_load_lds((g_u32*)ga,
                (l_u32*)&sA[buf][rd * 64 + w * 16][0], 16, 0, 0);
            __builtin_amdgcn_global_load_lds((g_u32*)gb,
                (l_u32*)&sB[buf][rd * 64 + w * 16][0], 16, 0, 0);
        }
    };

    stage(0, 0);
    int buf = 0;
    const int l15 = lane & 15;
    const int sl  = lane >> 4;       // logical k-slot (0..3)

    for (int kk = 0; kk < 1536; kk += 32) {
        __syncthreads();             // drains vmcnt: buf's tiles are resident
        if (kk + 32 < 1536) stage(buf ^ 1, kk + 32);

        bf16x8 afr[4], bfr[4];
        #pragma unroll
        for (int m = 0; m < 4; ++m) {
            int R   = wr * 64 + m * 16 + l15;
            int off = R * 32 + ((sl ^ ((R >> 1) & 3)) * 8);
            afr[m] = *(const bf16x8*)(&sA[buf][0][0] + off);
        }
        #pragma unroll
        for (int n = 0; n < 4; ++n) {
            int Ccol = wc * 64 + n * 16 + l15;
            int off  = Ccol * 32 + ((sl ^ ((Ccol >> 1) & 3)) * 8);
            bfr[n] = *(const bf16x8*)(&sB[buf][0][0] + off);
        }
        #pragma unroll
        for (int m = 0; m < 4; ++m)
            #pragma unroll
            for (int n = 0; n < 4; ++n)
                acc[m][n] = __builtin_amdgcn_mfma_f32_16x16x32_bf16(
                                afr[m], bfr[n], acc[m][n], 0, 0, 0);
        buf ^= 1;
    }

    // epilogue: C/D layout col = lane&15, row = (lane>>4)*4 + reg
    const int lg = lane >> 4;
    #pragma unroll
    for (int m = 0; m < 4; ++m) {
        int row = tileM + wr * 64 + m * 16 + lg * 4;
        #pragma unroll
        for (int n = 0; n < 4; ++n) {
            int col = tileN + wc * 64 + n * 16 + l15;
            float bv = bias[col];
            #pragma unroll
            for (int r = 0; r < 4; ++r)
                C[(size_t)(row + r) * OO + col] = acc[m][n][r] + bv;
        }
    }
}

// ---------------------------------------------------------------------------
// Gather embedding row + build concatenated inputs
// ---------------------------------------------------------------------------
__global__ void gather_embed(const int* __restrict__ ids,
                             const float* __restrict__ emb,
                             const float* __restrict__ hidden,
                             float* __restrict__ cat_eh,
                             float* __restrict__ cat_ea)
{
    int idx = blockIdx.x * blockDim.x + threadIdx.x;   // N*H
    int n = idx >> 9, k = idx & 511;
    float e = emb[(size_t)ids[n] * HH + k];
    cat_eh[(size_t)n * 1024 + k] = e;
    cat_ea[(size_t)n * 1024 + k] = e;
    cat_eh[(size_t)n * 1024 + 512 + k] = hidden[idx];
}

// ---------------------------------------------------------------------------
// Softmax over L=128, one block (128 threads) per row
// ---------------------------------------------------------------------------
__global__ void softmax128(const float* __restrict__ logits,
                           float* __restrict__ w_out)
{
    int n = blockIdx.x;
    int t = threadIdx.x;   // 128
    __shared__ float buf[128];
    float v = logits[(size_t)n * LL + t];
    buf[t] = v;
    __syncthreads();
    for (int s = 64; s > 0; s >>= 1) {
        if (t < s) buf[t] = fmaxf(buf[t], buf[t + s]);
        __syncthreads();
    }
    float m = buf[0];
    __syncthreads();
    float e = expf(v - m);
    buf[t] = e;
    __syncthreads();
    for (int s = 64; s > 0; s >>= 1) {
        if (t < s) buf[t] += buf[t + s];
        __syncthreads();
    }
    float s = buf[0];
    w_out[(size_t)n * LL + t] = e / s;
}

// ---------------------------------------------------------------------------
// attn_applied[n][h] = sum_l w[n][l] * enc[n][l][h] * mask[n][l][h]
// ---------------------------------------------------------------------------
__global__ __launch_bounds__(256) void attn_apply(
    const float* __restrict__ w, const float* __restrict__ enc,
    const float* __restrict__ mask, float* __restrict__ cat_ea)
{
    int n = blockIdx.x;
    int t = threadIdx.x;   // 256
    __shared__ float wl[LL];
    if (t < LL) wl[t] = w[(size_t)n * LL + t];
    __syncthreads();
    const float2* ep = (const float2*)(enc + (size_t)n * LL * HH);
    const float2* mp = (const float2*)(mask + (size_t)n * LL * HH);
    float2 acc = {0.f, 0.f};
    #pragma unroll 4
    for (int l = 0; l < LL; ++l) {
        float wv = wl[l];
        float2 e = ep[l * (HH / 2) + t];
        float2 m = mp[l * (HH / 2) + t];
        acc.x += wv * e.x * m.x;
        acc.y += wv * e.y * m.y;
    }
    ((float2*)(cat_ea + (size_t)n * 1024 + 512))[t] = acc;
}

// ---------------------------------------------------------------------------
// GRU elementwise:  r,z,n gates -> h_new  (+ optional bf16 hi/lo split of h)
// ---------------------------------------------------------------------------
__global__ void gru_elem(const float* __restrict__ gx,
                         const float* __restrict__ gh,
                         const float* __restrict__ hidden,
                         float* __restrict__ h_new,
                         unsigned short* __restrict__ A2)
{
    int idx = blockIdx.x * blockDim.x + threadIdx.x;   // N*H
    int n = idx >> 9, h = idx & 511;
    const float* gxr = gx + (size_t)n * 1536;
    const float* ghr = gh + (size_t)n * 1536;
    float r = 1.f / (1.f + expf(-(gxr[h] + ghr[h])));
    float z = 1.f / (1.f + expf(-(gxr[512 + h] + ghr[512 + h])));
    float nn = tanhf(gxr[1024 + h] + r * ghr[1024 + h]);
    float hp = hidden[idx];
    float hv = (1.f - z) * nn + z * hp;
    h_new[idx] = hv;
    if (A2) {
        unsigned short hi = f2bf(hv);
        A2[(size_t)n * 1024 + h]       = hi;
        A2[(size_t)n * 1024 + 512 + h] = f2bf(hv - bf2f(hi));
    }
}

// ---------------------------------------------------------------------------
// In-place log_softmax per row of length O, one block (256 threads) per row
// ---------------------------------------------------------------------------
__global__ __launch_bounds__(256) void logsoftmax_rows(float* __restrict__ out)
{
    int n = blockIdx.x;
    int t = threadIdx.x;   // 256
    float* row = out + (size_t)n * OO;
    float m = -INFINITY, s = 0.f;
    for (int o = t; o < OO; o += 256) {
        float v = row[o];
        if (v > m) { s = s * expf(m - v) + 1.f; m = v; }
        else       { s += expf(v - m); }
    }
    __shared__ float ms[256], ss[256];
    ms[t] = m; ss[t] = s;
    __syncthreads();
    for (int st = 128; st > 0; st >>= 1) {
        if (t < st) {
            float m2 = ms[t + st], s2 = ss[t + st];
            float mm = fmaxf(ms[t], m2);
            ss[t] = ss[t] * expf(ms[t] - mm) + s2 * expf(m2 - mm);
            ms[t] = mm;
        }
        __syncthreads();
    }
    float lse = ms[0] + logf(ss[0]);
    for (int o = t; o < OO; o += 256) row[o] -= lse;
}

// ---------------------------------------------------------------------------
extern "C" void kernel_launch(void* const* d_in, const int* in_sizes, int n_in,
                              void* d_out, int out_size, void* d_ws, size_t ws_size,
                              hipStream_t stream)
{
    const int*   input_ids = (const int*)  d_in[0];
    const float* hidden    = (const float*)d_in[1];
    const float* enc       = (const float*)d_in[2];
    const float* mask      = (const float*)d_in[3];
    const float* emb       = (const float*)d_in[4];
    const float* attn_W    = (const float*)d_in[5];
    const float* attn_b    = (const float*)d_in[6];
    const float* comb_W    = (const float*)d_in[7];
    const float* comb_b    = (const float*)d_in[8];
    const float* W_ih      = (const float*)d_in[9];
    const float* W_hh      = (const float*)d_in[10];
    const float* b_ih      = (const float*)d_in[11];
    const float* b_hh      = (const float*)d_in[12];
    const float* out_W     = (const float*)d_in[13];
    const float* out_b     = (const float*)d_in[14];

    float* out      = (float*)d_out;
    float* out_logp = out;                                  // [N,O]
    float* out_h    = out + (size_t)NB * OO;                // [N,H]
    float* out_w    = out + (size_t)NB * OO + NB * HH;      // [N,L]

    float* ws          = (float*)d_ws;
    float* cat_eh      = ws;                    // N*2H = 1048576
    float* cat_ea      = ws + 1048576;          // N*2H = 1048576
    float* attn_logits = ws + 2097152;          // N*L  = 131072
    float* xbuf        = ws + 2228224;          // N*H  = 524288
    float* gx          = ws + 2752512;          // N*3H = 1572864
    float* gh          = ws + 4325376;          // N*3H = 1572864
    // base total 5898240 floats = 23.6 MB
    // bf16x3 extension:
    //   A2 (h_new hi|lo):  1024*1024 ushort = 524288 floats  @ 5898240
    //   B2 (out_W hi|lo): 32000*1024 ushort = 16384000 floats @ 6422528
    const size_t WS_NEED = (size_t)(5898240 + 524288 + 16384000) * 4;  // 91.2 MB
    const bool fast = ws_size >= WS_NEED;
    unsigned short* A2 = fast ? (unsigned short*)(ws + 5898240) : nullptr;
    unsigned short* B2 = fast ? (unsigned short*)(ws + 6422528) : nullptr;

    // 0. split out_W into bf16 hi|lo (independent of everything else)
    if (fast)
        split_w<<<16000, 256, 0, stream>>>(out_W, B2);
    // 1. gather embedding + build concatenations
    gather_embed<<<(NB * HH) / 256, 256, 0, stream>>>(input_ids, emb, hidden,
                                                      cat_eh, cat_ea);
    // 2. attention logits: [N,2H] @ [L,2H]^T + b
    sgemm_bias<0><<<dim3(LL / 64, NB / 64), 256, 0, stream>>>(
        cat_eh, attn_W, attn_b, attn_logits, NB, LL, 2 * HH);
    // 3. softmax over L -> attn_weights (output 2)
    softmax128<<<NB, 128, 0, stream>>>(attn_logits, out_w);
    // 4. weighted sum over masked encoder outputs -> cat_ea second half
    attn_apply<<<NB, 256, 0, stream>>>(out_w, enc, mask, cat_ea);
    // 5. combine + relu: [N,2H] @ [H,2H]^T + b
    sgemm_bias<1><<<dim3(HH / 64, NB / 64), 256, 0, stream>>>(
        cat_ea, comb_W, comb_b, xbuf, NB, HH, 2 * HH);
    // 6/7. GRU input & hidden projections: [N,H] @ [3H,H]^T + b
    sgemm_bias<0><<<dim3((3 * HH) / 64, NB / 64), 256, 0, stream>>>(
        xbuf, W_ih, b_ih, gx, NB, 3 * HH, HH);
    sgemm_bias<0><<<dim3((3 * HH) / 64, NB / 64), 256, 0, stream>>>(
        hidden, W_hh, b_hh, gh, NB, 3 * HH, HH);
    // 8. GRU gates -> h_new (output 1) + bf16 split for MFMA GEMM
    gru_elem<<<(NB * HH) / 256, 256, 0, stream>>>(gx, gh, hidden, out_h, A2);
    // 9. output projection: [N,H] @ [O,H]^T + b -> logits in d_out
    if (fast)
        gemm_bf16x3<<<2000, 256, 0, stream>>>(A2, B2, out_b, out_logp);
    else
        sgemm_bias<0><<<dim3(OO / 64, NB / 64), 256, 0, stream>>>(
            out_h, out_W, out_b, out_logp, NB, OO, HH);
    // 10. in-place log_softmax
    logsoftmax_rows<<<NB, 256, 0, stream>>>(out_logp);
}